// Round 6
// baseline (234.461 us; speedup 1.0000x reference)
//
#include <hip/hip_runtime.h>
#include <cstdint>

// Problem sizes (fixed by reference)
#define S_    2048
#define DM    1024
#define DH    4096
#define NTOK  8192     // B*S = 4*2048
#define WELEM 4194304  // 4096*1024 elements in each weight matrix
#define CT    8        // tokens per conv block

typedef int v4i __attribute__((ext_vector_type(4)));
typedef _Float16 half8 __attribute__((ext_vector_type(8)));
typedef char char8v __attribute__((ext_vector_type(8)));

// async global->LDS, 16B per lane, dest = wave-uniform base (+ lane*16 by HW)
#define GLOAD_LDS16(g, l)                                                   \
    __builtin_amdgcn_global_load_lds(                                       \
        (const __attribute__((address_space(1))) void*)(g),                 \
        (__attribute__((address_space(3))) void*)(l), 16, 0, 0)

// raw barrier (no implicit vmcnt(0) drain) + compiler memory fence
static __device__ __forceinline__ void sbar() {
    asm volatile("" ::: "memory");
    __builtin_amdgcn_s_barrier();
    asm volatile("" ::: "memory");
}
#define LGKM0() asm volatile("s_waitcnt lgkmcnt(0)" ::: "memory")
#define VMC0() asm volatile("s_waitcnt vmcnt(0)" ::: "memory")
#define VMC3() asm volatile("s_waitcnt vmcnt(3)" ::: "memory")
#define VMC4() asm volatile("s_waitcnt vmcnt(4)" ::: "memory")
#define VMC8() asm volatile("s_waitcnt vmcnt(8)" ::: "memory")

// ---------------------------------------------------------------------------
// Per-block partial sums of |w| in fp64, both matrices in one launch.
__global__ __launch_bounds__(256) void absmean_partial(const float4* __restrict__ wa,
                                                       const float4* __restrict__ wb,
                                                       double* __restrict__ partial) {
    __shared__ double red[256];
    const float4* w = (blockIdx.x < 1024) ? wa : wb;
    int base = (blockIdx.x & 1023) * 1024;  // in float4 units
    double s = 0.0;
#pragma unroll
    for (int k = 0; k < 4; ++k) {
        float4 v = w[base + (k << 8) + threadIdx.x];
        s += (double)fabsf(v.x) + (double)fabsf(v.y) +
             (double)fabsf(v.z) + (double)fabsf(v.w);
    }
    red[threadIdx.x] = s;
    __syncthreads();
    for (int off = 128; off > 0; off >>= 1) {
        if (threadIdx.x < off) red[threadIdx.x] += red[threadIdx.x + off];
        __syncthreads();
    }
    if (threadIdx.x == 0) partial[blockIdx.x] = red[0];
}

// Deterministic tree-sum of partials; scale = 1/clip(mean,1e-5) fp32.
__global__ __launch_bounds__(256) void finalize_scales(const double* __restrict__ part,
                                                       float* __restrict__ sc) {
    __shared__ double red[1024];
#pragma unroll 1
    for (int m = 0; m < 2; ++m) {
        const double* p = part + m * 1024;
        __syncthreads();
#pragma unroll
        for (int k = 0; k < 4; ++k) red[(k << 8) + threadIdx.x] = p[(k << 8) + threadIdx.x];
        __syncthreads();
        double s = red[threadIdx.x] + red[threadIdx.x + 256] +
                   red[threadIdx.x + 512] + red[threadIdx.x + 768];
        __syncthreads();
        red[threadIdx.x] = s;
        __syncthreads();
        for (int off = 128; off > 0; off >>= 1) {
            if (threadIdx.x < off) red[threadIdx.x] += red[threadIdx.x + off];
            __syncthreads();
        }
        if (threadIdx.x == 0) {
            double mean = red[0] / (double)WELEM;
            float mf = fmaxf((float)mean, 1e-5f);
            float scale = 1.0f / mf;
            sc[2 * m]     = scale;
            sc[2 * m + 1] = 1.0f / scale;
        }
    }
}

// One launch: blocks [0,8192) ternary-quantize w1/w2; [8192,16384) int8-quantize x.
__global__ __launch_bounds__(256) void quant_all(const float4* __restrict__ w1,
                                                 const float4* __restrict__ w2,
                                                 const float4* __restrict__ x,
                                                 char4* __restrict__ qw1,
                                                 char4* __restrict__ qw2,
                                                 char4* __restrict__ qx,
                                                 float* __restrict__ dqx,
                                                 const float* __restrict__ sc) {
    __shared__ float red[256];
    if (blockIdx.x < 8192) {
        bool second = blockIdx.x >= 4096;
        const float4* w = second ? w2 : w1;
        char4* q = second ? qw2 : qw1;
        float scale = sc[second ? 2 : 0];
        int i = (blockIdx.x & 4095) * 256 + threadIdx.x;
        float4 v = w[i];
        char4 o;
        o.x = (signed char)(int)fminf(fmaxf(rintf(v.x * scale), -1.f), 1.f);
        o.y = (signed char)(int)fminf(fmaxf(rintf(v.y * scale), -1.f), 1.f);
        o.z = (signed char)(int)fminf(fmaxf(rintf(v.z * scale), -1.f), 1.f);
        o.w = (signed char)(int)fminf(fmaxf(rintf(v.w * scale), -1.f), 1.f);
        q[i] = o;
    } else {
        int t = blockIdx.x - 8192;
        float4 v = x[(size_t)t * 256 + threadIdx.x];
        float mx = fmaxf(fmaxf(fabsf(v.x), fabsf(v.y)), fmaxf(fabsf(v.z), fabsf(v.w)));
        red[threadIdx.x] = mx;
        __syncthreads();
        for (int off = 128; off > 0; off >>= 1) {
            if (threadIdx.x < off) red[threadIdx.x] = fmaxf(red[threadIdx.x], red[threadIdx.x + off]);
            __syncthreads();
        }
        float scale = 127.0f / fmaxf(red[0], 1e-5f);
        // |v|*scale <= 127 by construction -> clamps redundant
        char4 o;
        o.x = (signed char)(int)rintf(v.x * scale);
        o.y = (signed char)(int)rintf(v.y * scale);
        o.z = (signed char)(int)rintf(v.z * scale);
        o.w = (signed char)(int)rintf(v.w * scale);
        qx[(size_t)t * 256 + threadIdx.x] = o;
        if (threadIdx.x == 0) dqx[t] = 1.0f / scale;
    }
}

// Fused depthwise conv3 (+bias) + SiLU + per-token int8 quant over DH=4096.
// SiLU via v_exp_f32/v_rcp_f32; quant clamps dropped (|v*scale| <= 127 by
// construction of scale).
__global__ __launch_bounds__(512) void conv_silu_quant(const half8* __restrict__ h,
                                                       const float4* __restrict__ cwv,
                                                       const float4* __restrict__ cbv,
                                                       char8v* __restrict__ q,
                                                       float* __restrict__ dq) {
    __shared__ float red[2][8];
    const int tid = threadIdx.x;
    const int t0 = blockIdx.x * CT;
    const int s0 = t0 & (S_ - 1);      // CT | S_, block never straddles batches

    float wc[24], bs[8];
    {
        float4 tmp;
#pragma unroll
        for (int i = 0; i < 6; ++i) {
            tmp = cwv[tid * 6 + i];
            wc[4 * i] = tmp.x; wc[4 * i + 1] = tmp.y; wc[4 * i + 2] = tmp.z; wc[4 * i + 3] = tmp.w;
        }
        tmp = cbv[tid * 2];     bs[0] = tmp.x; bs[1] = tmp.y; bs[2] = tmp.z; bs[3] = tmp.w;
        tmp = cbv[tid * 2 + 1]; bs[4] = tmp.x; bs[5] = tmp.y; bs[6] = tmp.z; bs[7] = tmp.w;
    }

    auto ldrow = [&](int t, bool valid, float* dst) {
        if (valid) {
            half8 raw = h[(size_t)t * 512 + tid];
#pragma unroll
            for (int e = 0; e < 8; ++e) dst[e] = (float)raw[e];
        } else {
#pragma unroll
            for (int e = 0; e < 8; ++e) dst[e] = 0.f;
        }
    };

    float pv[8], cu[8], nx[8], pf[8];
    ldrow(t0 - 1, s0 > 0, pv);
    ldrow(t0, true, cu);
    ldrow(t0 + 1, true, nx);

#pragma unroll
    for (int i = 0; i < CT; ++i) {
        const int t = t0 + i;
        ldrow(t + 2, (s0 + i + 2) < S_, pf);

        float v[8];
        float mx = 0.f;
#pragma unroll
        for (int e = 0; e < 8; ++e) {
            float y = wc[3 * e] * pv[e] + wc[3 * e + 1] * cu[e] + wc[3 * e + 2] * nx[e] + bs[e];
            // silu(y) = y * sigmoid(y) = y * rcp(1 + 2^(-y*log2e))
            float ex = __builtin_amdgcn_exp2f(-1.44269504088896f * y);
            float r  = y * __builtin_amdgcn_rcpf(1.0f + ex);
            v[e] = r;
            mx = fmaxf(mx, fabsf(r));
        }
#pragma unroll
        for (int off = 32; off > 0; off >>= 1)
            mx = fmaxf(mx, __shfl_down(mx, off, 64));
        if ((tid & 63) == 0) red[i & 1][tid >> 6] = mx;
        __syncthreads();
        float rmax = red[i & 1][0];
#pragma unroll
        for (int w = 1; w < 8; ++w) rmax = fmaxf(rmax, red[i & 1][w]);
        float scale = 127.0f / fmaxf(rmax, 1e-5f);
        char8v o;
#pragma unroll
        for (int e = 0; e < 8; ++e)
            o[e] = (signed char)(int)rintf(v[e] * scale);
        q[(size_t)t * 512 + tid] = o;
        if (tid == 0) dq[t] = 1.0f / scale;
#pragma unroll
        for (int e = 0; e < 8; ++e) { pv[e] = cu[e]; cu[e] = nx[e]; nx[e] = pf[e]; }
    }
}

// ---------------------------------------------------------------------------
// GEMM1 round 6: faithful m201-style fine-phase schedule, i8 adaptation.
// BM=BN=256, BK=64, 8 waves as 2(M)x4(N), wave-tile 128x64, acc[8][4].
// Ring-4 LDS (4 x 32KB = 128KB), 1 block/CU, __launch_bounds__(512,2)
// -> 256 unified regs/wave (acc 128 AGPR + ~90 VGPR, no spill).
//
// r5 post-mortem: coarse {read-all|stage-all|mfma-all|vmcnt|bar} per K-tile
// gave identical ~3700cyc/tile across two very different wave configs ->
// schedule-limited ("2ph" regime; guide m196/m218/m228: T2/T5 null there,
// fine 8-phase interleave is the lever, 62% MfmaUtil at 1 block/CU).
//
// Per K-tile t, TWO phases (m201 pattern):
//  ph0: ds_read bf[0..3],af[0..3](buf t) | stageA(t+3) | BAR | lgkm0 |
//       prio1 16xMFMA(acc[0..3]) prio0 | BAR
//  ph1: ds_read af[4..7](buf t)          | stageB(t+3) | BAR | lgkm0 |
//       prio1 16xMFMA(acc[4..7]) prio0 | vmcnt(8) | BAR
// Counted vmcnt once per K-tile: outstanding at wait = t+2's 4 + t+3's 4;
// vmcnt(8) guarantees t+1's loads (issued during t-2, ~3 tile-times of
// lookahead) retired; the barrier makes it cross-wave. Tail: 8 -> 4 -> 0.
// Recycle: stage(t+3) overwrites buf[t-1], issued after the end-of-(t-1)
// barrier behind which every wave's buf[t-1] reads retired (reads preceded
// that wave's MFMAs via data dep, which preceded its barrier).
//
// Swizzle (64B LDS rows, verified conflict-free r2-r5): phys_chunk =
// chunk ^ ((row>>1)&3), involution on staging source and ds_read.
__global__ __launch_bounds__(512, 2)
void gemm1_8ph(const int8_t* __restrict__ A, const int8_t* __restrict__ Bm,
               _Float16* __restrict__ C, const float* __restrict__ rowdq,
               const float* __restrict__ sc, int slot, int N, int K) {
    __shared__ __align__(16) int8_t lds[4][32768];   // [ring][A 16KB | B 16KB]
    const int tid  = threadIdx.x;
    const int lane = tid & 63;
    const int wave = tid >> 6;

    // XCD-chunked bijective swizzle (grid 512, multiple of 8)
    const int nwg = gridDim.x * gridDim.y;
    int flat = blockIdx.y * gridDim.x + blockIdx.x;
    flat = (flat & 7) * (nwg >> 3) + (flat >> 3);
    const int bx = flat % gridDim.x;
    const int by = flat / gridDim.x;
    const int mbase = by << 8;               // BM=256
    const int nbase = bx << 8;               // BN=256
    const int NT = K >> 6;

    const int wm = wave >> 2;                // 0..1  (128-row half)
    const int wn = wave & 3;                 // 0..3  (64-col quarter)

    // ---- staging: wave w covers A rows [32w,32w+32) and B rows [32w,32w+32),
    // 2 gloads each (1KB = 16 rows x 64B). Inverse swizzle on global source.
    const int srow = lane >> 2;                               // row within 1KB unit
    const int csrc = (((lane & 3) ^ ((lane >> 3) & 3)) << 4); // logical 16B chunk
    const int8_t* Ag = A  + (size_t)(mbase + wave * 32 + srow) * K + csrc;
    const int8_t* Bg = Bm + (size_t)(nbase + wave * 32 + srow) * K + csrc;

    auto stageA = [&](int s, int tt) {
        const size_t ko = (size_t)tt << 6;
        int8_t* d = &lds[s][wave << 11];
        GLOAD_LDS16(Ag + ko,                  d);
        GLOAD_LDS16(Ag + ko + (size_t)16 * K, d + 1024);
    };
    auto stageB = [&](int s, int tt) {
        const size_t ko = (size_t)tt << 6;
        int8_t* d = &lds[s][16384 + (wave << 11)];
        GLOAD_LDS16(Bg + ko,                  d);
        GLOAD_LDS16(Bg + ko + (size_t)16 * K, d + 1024);
    };

    // ---- frag read offsets (i8 16x16x64: row = lane&15, chunk = lane>>4)
    const int fc   = (((lane >> 4) ^ ((lane >> 1) & 3)) << 4);    // swizzled chunk
    const int aoff = ((wm * 128 + (lane & 15)) << 6) + fc;        // + i*1024, i=0..7
    const int boff = 16384 + ((wn * 64 + (lane & 15)) << 6) + fc; // + j*1024

    v4i acc[8][4] = {};

    // prologue: 3 tiles in flight (prefetch distance 3); counted wait for tile 0
    stageA(0, 0); stageB(0, 0);
    if (NT > 1) { stageA(1, 1); stageB(1, 1); }
    if (NT > 2) { stageA(2, 2); stageB(2, 2); }
    if (NT > 2)      VMC8();
    else if (NT > 1) VMC4();
    else             VMC0();
    sbar();

    for (int t = 0; t < NT; ++t) {
        const int8_t* base = &lds[t & 3][0];
        const int s3 = (t + 3) & 3;

        // ---------------- phase 0 ----------------
        v4i bf[4], af[4];
#pragma unroll
        for (int j = 0; j < 4; ++j)
            bf[j] = *reinterpret_cast<const v4i*>(base + boff + (j << 10));
#pragma unroll
        for (int i = 0; i < 4; ++i)
            af[i] = *reinterpret_cast<const v4i*>(base + aoff + (i << 10));
        if (t + 3 < NT) stageA(s3, t + 3);
        sbar();
        LGKM0();
        __builtin_amdgcn_s_setprio(1);
#pragma unroll
        for (int i = 0; i < 4; ++i)
#pragma unroll
            for (int j = 0; j < 4; ++j)
                acc[i][j] = __builtin_amdgcn_mfma_i32_16x16x64_i8(af[i], bf[j], acc[i][j], 0, 0, 0);
        __builtin_amdgcn_s_setprio(0);
        sbar();

        // ---------------- phase 1 ----------------
#pragma unroll
        for (int i = 0; i < 4; ++i)
            af[i] = *reinterpret_cast<const v4i*>(base + aoff + ((i + 4) << 10));
        if (t + 3 < NT) stageB(s3, t + 3);
        sbar();
        LGKM0();
        __builtin_amdgcn_s_setprio(1);
#pragma unroll
        for (int i = 0; i < 4; ++i)
#pragma unroll
            for (int j = 0; j < 4; ++j)
                acc[i + 4][j] = __builtin_amdgcn_mfma_i32_16x16x64_i8(af[i], bf[j], acc[i + 4][j], 0, 0, 0);
        __builtin_amdgcn_s_setprio(0);

        // counted wait: guarantee tile t+1's loads retired (newer: t+2,t+3)
        if (t + 3 < NT)      VMC8();
        else if (t + 2 < NT) VMC4();
        else if (t + 1 < NT) VMC0();
        sbar();
    }

    // ---------------- epilogue ----------------
    const float wdq = sc[slot];
    const int quad = lane >> 4;
    const int col  = lane & 15;
#pragma unroll
    for (int i = 0; i < 8; ++i) {
#pragma unroll
        for (int r = 0; r < 4; ++r) {
            int m = mbase + (wm << 7) + (i << 4) + (quad << 2) + r;  // row=(lane>>4)*4+reg
            float rs = rowdq[m] * wdq;
#pragma unroll
            for (int j = 0; j < 4; ++j) {
                int n = nbase + (wn << 6) + (j << 4) + col;          // col=lane&15
                C[(size_t)m * N + n] = (_Float16)((float)acc[i][j][r] * rs);
            }
        }
    }
}

// ---------------------------------------------------------------------------
// GEMM2 kernel (grid-constrained by N=1024): BM=128/BN=128, 4 waves, BK=64,
// 3-deep ring, one barrier per tile, counted vmcnt. Unchanged from r3.
template <int BM, int WAVES, typename OutT>
__global__ __launch_bounds__(WAVES * 64, (BM == 256) ? 4 : 3)
void gemm_i8_bk64(const int8_t* __restrict__ A, const int8_t* __restrict__ Bm,
                  OutT* __restrict__ C, const float* __restrict__ rowdq,
                  const float* __restrict__ sc, int slot, int N, int K) {
    constexpr int BN = 128;
    constexpr int ABYTES = BM * 64;           // A bytes per ring buffer
    constexpr int BUF = (BM + BN) * 64;       // bytes per ring buffer
    constexpr int ALOADS = BM / 16 / WAVES;   // per-wave 1KB A loads per tile
    constexpr int BLOADS = BN / 16 / WAVES;   // per-wave 1KB B loads per tile
    constexpr int L = ALOADS + BLOADS;        // per-wave loads per tile

    __shared__ __align__(16) int8_t lds[3][BUF];
    const int tid  = threadIdx.x;
    const int lane = tid & 63;
    const int wave = tid >> 6;

    // XCD-chunked bijective swizzle (grid is a multiple of 8)
    const int nwg = gridDim.x * gridDim.y;
    int flat = blockIdx.y * gridDim.x + blockIdx.x;
    flat = (flat & 7) * (nwg >> 3) + (flat >> 3);
    const int bx = flat % gridDim.x;
    const int by = flat / gridDim.x;
    const int mbase = by * BM;
    const int nbase = bx << 7;
    const int NT = K >> 6;

    const int wm = wave >> 1;                 // m 64-row slab
    const int wn = wave & 1;                  // n 64-col half

    // ---- staging source addressing (inverse swizzle on global side)
    const int srow = lane >> 2;                               // row within 1KB load
    const int csrc = (((lane & 3) ^ ((lane >> 3) & 3)) << 4); // logical 16B chunk
    const int8_t* Ag = A  + (size_t)(mbase + wave * (ALOADS * 16) + srow) * K + csrc;
    const int8_t* Bg = Bm + (size_t)(nbase + wave * (BLOADS * 16) + srow) * K + csrc;

    auto stage = [&](int s, int tt) {
        const size_t ko = (size_t)tt << 6;
        int8_t* dA = &lds[s][(wave * ALOADS) << 10];
        int8_t* dB = &lds[s][ABYTES + ((wave * BLOADS) << 10)];
#pragma unroll
        for (int l = 0; l < ALOADS; ++l)
            GLOAD_LDS16(Ag + ko + (size_t)(l * 16) * K, dA + (l << 10));
#pragma unroll
        for (int l = 0; l < BLOADS; ++l)
            GLOAD_LDS16(Bg + ko + (size_t)(l * 16) * K, dB + (l << 10));
    };

    // ---- frag read offsets (i8 16x16x64: row = lane&15, chunk = lane>>4)
    const int fc   = (((lane >> 4) ^ ((lane >> 1) & 3)) << 4);  // swizzled chunk
    const int aoff = ((wm * 64 + (lane & 15)) << 6) + fc;       // + i*1024
    const int boff = ABYTES + ((wn * 64 + (lane & 15)) << 6) + fc;

    v4i acc[4][4] = {};

    // prologue: 2 tiles in flight; wait tile 0 (counted), cross-wave via barrier
    stage(0, 0);
    stage(1, 1);
    if constexpr (L == 3) VMC3(); else VMC4();
    sbar();

    int sb = 0;
    for (int t = 0; t < NT; ++t) {
        const int8_t* base = &lds[sb][0];
        v4i af[4], bf[4];
#pragma unroll
        for (int i = 0; i < 4; ++i)
            af[i] = *reinterpret_cast<const v4i*>(base + aoff + (i << 10));
#pragma unroll
        for (int j = 0; j < 4; ++j)
            bf[j] = *reinterpret_cast<const v4i*>(base + boff + (j << 10));
        int s2 = sb + 2; if (s2 >= 3) s2 -= 3;
        if (t + 2 < NT) stage(s2, t + 2);

        __builtin_amdgcn_s_setprio(1);
#pragma unroll
        for (int i = 0; i < 4; ++i)
#pragma unroll
            for (int j = 0; j < 4; ++j)
                acc[i][j] = __builtin_amdgcn_mfma_i32_16x16x64_i8(af[i], bf[j], acc[i][j], 0, 0, 0);
        __builtin_amdgcn_s_setprio(0);

        if (t + 2 < NT)      { if constexpr (L == 3) VMC3(); else VMC4(); }
        else if (t + 1 < NT) VMC0();
        sbar();
        if (++sb == 3) sb = 0;
    }

    // ---------------- epilogue ----------------
    const float wdq = sc[slot];
    const int quad = lane >> 4;
    const int col  = lane & 15;
#pragma unroll
    for (int i = 0; i < 4; ++i) {
#pragma unroll
        for (int r = 0; r < 4; ++r) {
            int m = mbase + (wm << 6) + (i << 4) + (quad << 2) + r;  // row=(lane>>4)*4+reg
            float rs = rowdq[m] * wdq;
#pragma unroll
            for (int j = 0; j < 4; ++j) {
                int n = nbase + (wn << 6) + (j << 4) + col;          // col=lane&15
                C[(size_t)m * N + n] = (OutT)((float)acc[i][j][r] * rs);
            }
        }
    }
}

// ---------------------------------------------------------------------------
extern "C" void kernel_launch(void* const* d_in, const int* in_sizes, int n_in,
                              void* d_out, int out_size, void* d_ws, size_t ws_size,
                              hipStream_t stream) {
    const float* x  = (const float*)d_in[0];  // [4,2048,1024]
    const float* w1 = (const float*)d_in[1];  // [4096,1024]
    const float* cw = (const float*)d_in[2];  // [4096,1,3]
    const float* cb = (const float*)d_in[3];  // [4096]
    const float* w2 = (const float*)d_in[4];  // [1024,4096]
    float* out = (float*)d_out;               // [4,2048,1024]
    char* ws = (char*)d_ws;

    // Workspace layout (16B-aligned)
    double* part  = (double*)(ws + 0);          // 2048 doubles
    float*  sc    = (float*)(ws + 16384);       // {scale_w1, dq_w1, scale_w2, dq_w2}
    float*  dqx   = (float*)(ws + 16640);       // 8192 floats
    float*  dqh   = (float*)(ws + 49408);       // 8192 floats
    int8_t* qw1   = (int8_t*)(ws + 82176);      // 4 MB
    int8_t* qw2   = (int8_t*)(ws + 4276480);    // 4 MB
    int8_t* qx    = (int8_t*)(ws + 8470784);    // 8 MB
    int8_t* qh    = (int8_t*)(ws + 16859392);   // 32 MB
    _Float16* h   = (_Float16*)(ws + 50413824); // 64 MB (fp16)

    absmean_partial<<<2048, 256, 0, stream>>>((const float4*)w1, (const float4*)w2, part);
    finalize_scales<<<1, 256, 0, stream>>>(part, sc);
    quant_all<<<16384, 256, 0, stream>>>((const float4*)w1, (const float4*)w2,
                                         (const float4*)x, (char4*)qw1, (char4*)qw2,
                                         (char4*)qx, dqx, sc);

    // GEMM1: M=8192, N=4096, K=1024 -> h (fp16); 512 blocks, 1 block/CU
    dim3 g1(DH / 256, NTOK / 256);
    gemm1_8ph<<<g1, 512, 0, stream>>>(qx, qw1, h, dqx, sc, 1, DH, DM);

    conv_silu_quant<<<NTOK / CT, 512, 0, stream>>>((const half8*)h, (const float4*)cw,
                                                   (const float4*)cb, (char8v*)qh, dqh);

    // GEMM2: M=8192, N=1024, K=4096 -> out (fp32); 512 blocks
    dim3 g2(DM / 128, NTOK / 128);
    gemm_i8_bk64<128, 4, float><<<g2, 256, 0, stream>>>(qh, qw2, out, dqh, sc, 3, DM, DH);
}

// Round 7
// 233.246 us; speedup vs baseline: 1.0052x; 1.0052x over previous
//
#include <hip/hip_runtime.h>
#include <cstdint>

// Problem sizes (fixed by reference)
#define S_    2048
#define DM    1024
#define DH    4096
#define NTOK  8192     // B*S = 4*2048
#define WELEM 4194304  // 4096*1024 elements in each weight matrix
#define CT    8        // tokens per conv block

typedef int v4i __attribute__((ext_vector_type(4)));
typedef _Float16 half8 __attribute__((ext_vector_type(8)));
typedef char char8v __attribute__((ext_vector_type(8)));

// async global->LDS, 16B per lane, dest = wave-uniform base (+ lane*16 by HW)
#define GLOAD_LDS16(g, l)                                                   \
    __builtin_amdgcn_global_load_lds(                                       \
        (const __attribute__((address_space(1))) void*)(g),                 \
        (__attribute__((address_space(3))) void*)(l), 16, 0, 0)

// raw barrier (no implicit vmcnt(0) drain) + compiler memory fence
static __device__ __forceinline__ void sbar() {
    asm volatile("" ::: "memory");
    __builtin_amdgcn_s_barrier();
    asm volatile("" ::: "memory");
}
#define LGKM0() asm volatile("s_waitcnt lgkmcnt(0)" ::: "memory")
#define VMC0() asm volatile("s_waitcnt vmcnt(0)" ::: "memory")
#define VMC3() asm volatile("s_waitcnt vmcnt(3)" ::: "memory")
#define VMC4() asm volatile("s_waitcnt vmcnt(4)" ::: "memory")

// ---------------------------------------------------------------------------
// Per-block partial sums of |w| in fp64, both matrices in one launch.
__global__ __launch_bounds__(256) void absmean_partial(const float4* __restrict__ wa,
                                                       const float4* __restrict__ wb,
                                                       double* __restrict__ partial) {
    __shared__ double red[256];
    const float4* w = (blockIdx.x < 1024) ? wa : wb;
    int base = (blockIdx.x & 1023) * 1024;  // in float4 units
    double s = 0.0;
#pragma unroll
    for (int k = 0; k < 4; ++k) {
        float4 v = w[base + (k << 8) + threadIdx.x];
        s += (double)fabsf(v.x) + (double)fabsf(v.y) +
             (double)fabsf(v.z) + (double)fabsf(v.w);
    }
    red[threadIdx.x] = s;
    __syncthreads();
    for (int off = 128; off > 0; off >>= 1) {
        if (threadIdx.x < off) red[threadIdx.x] += red[threadIdx.x + off];
        __syncthreads();
    }
    if (threadIdx.x == 0) partial[blockIdx.x] = red[0];
}

// Deterministic tree-sum of partials; scale = 1/clip(mean,1e-5) fp32.
__global__ __launch_bounds__(256) void finalize_scales(const double* __restrict__ part,
                                                       float* __restrict__ sc) {
    __shared__ double red[1024];
#pragma unroll 1
    for (int m = 0; m < 2; ++m) {
        const double* p = part + m * 1024;
        __syncthreads();
#pragma unroll
        for (int k = 0; k < 4; ++k) red[(k << 8) + threadIdx.x] = p[(k << 8) + threadIdx.x];
        __syncthreads();
        double s = red[threadIdx.x] + red[threadIdx.x + 256] +
                   red[threadIdx.x + 512] + red[threadIdx.x + 768];
        __syncthreads();
        red[threadIdx.x] = s;
        __syncthreads();
        for (int off = 128; off > 0; off >>= 1) {
            if (threadIdx.x < off) red[threadIdx.x] += red[threadIdx.x + off];
            __syncthreads();
        }
        if (threadIdx.x == 0) {
            double mean = red[0] / (double)WELEM;
            float mf = fmaxf((float)mean, 1e-5f);
            float scale = 1.0f / mf;
            sc[2 * m]     = scale;
            sc[2 * m + 1] = 1.0f / scale;
        }
    }
}

// One launch: blocks [0,8192) ternary-quantize w1/w2; [8192,16384) int8-quantize x.
__global__ __launch_bounds__(256) void quant_all(const float4* __restrict__ w1,
                                                 const float4* __restrict__ w2,
                                                 const float4* __restrict__ x,
                                                 char4* __restrict__ qw1,
                                                 char4* __restrict__ qw2,
                                                 char4* __restrict__ qx,
                                                 float* __restrict__ dqx,
                                                 const float* __restrict__ sc) {
    __shared__ float red[256];
    if (blockIdx.x < 8192) {
        bool second = blockIdx.x >= 4096;
        const float4* w = second ? w2 : w1;
        char4* q = second ? qw2 : qw1;
        float scale = sc[second ? 2 : 0];
        int i = (blockIdx.x & 4095) * 256 + threadIdx.x;
        float4 v = w[i];
        char4 o;
        o.x = (signed char)(int)fminf(fmaxf(rintf(v.x * scale), -1.f), 1.f);
        o.y = (signed char)(int)fminf(fmaxf(rintf(v.y * scale), -1.f), 1.f);
        o.z = (signed char)(int)fminf(fmaxf(rintf(v.z * scale), -1.f), 1.f);
        o.w = (signed char)(int)fminf(fmaxf(rintf(v.w * scale), -1.f), 1.f);
        q[i] = o;
    } else {
        int t = blockIdx.x - 8192;
        float4 v = x[(size_t)t * 256 + threadIdx.x];
        float mx = fmaxf(fmaxf(fabsf(v.x), fabsf(v.y)), fmaxf(fabsf(v.z), fabsf(v.w)));
        red[threadIdx.x] = mx;
        __syncthreads();
        for (int off = 128; off > 0; off >>= 1) {
            if (threadIdx.x < off) red[threadIdx.x] = fmaxf(red[threadIdx.x], red[threadIdx.x + off]);
            __syncthreads();
        }
        float scale = 127.0f / fmaxf(red[0], 1e-5f);
        // |v|*scale <= 127 by construction -> clamps redundant
        char4 o;
        o.x = (signed char)(int)rintf(v.x * scale);
        o.y = (signed char)(int)rintf(v.y * scale);
        o.z = (signed char)(int)rintf(v.z * scale);
        o.w = (signed char)(int)rintf(v.w * scale);
        qx[(size_t)t * 256 + threadIdx.x] = o;
        if (threadIdx.x == 0) dqx[t] = 1.0f / scale;
    }
}

// Fused depthwise conv3 (+bias) + SiLU + per-token int8 quant over DH=4096.
// SiLU via v_exp_f32/v_rcp_f32; quant clamps dropped (|v*scale| <= 127 by
// construction of scale).
__global__ __launch_bounds__(512) void conv_silu_quant(const half8* __restrict__ h,
                                                       const float4* __restrict__ cwv,
                                                       const float4* __restrict__ cbv,
                                                       char8v* __restrict__ q,
                                                       float* __restrict__ dq) {
    __shared__ float red[2][8];
    const int tid = threadIdx.x;
    const int t0 = blockIdx.x * CT;
    const int s0 = t0 & (S_ - 1);      // CT | S_, block never straddles batches

    float wc[24], bs[8];
    {
        float4 tmp;
#pragma unroll
        for (int i = 0; i < 6; ++i) {
            tmp = cwv[tid * 6 + i];
            wc[4 * i] = tmp.x; wc[4 * i + 1] = tmp.y; wc[4 * i + 2] = tmp.z; wc[4 * i + 3] = tmp.w;
        }
        tmp = cbv[tid * 2];     bs[0] = tmp.x; bs[1] = tmp.y; bs[2] = tmp.z; bs[3] = tmp.w;
        tmp = cbv[tid * 2 + 1]; bs[4] = tmp.x; bs[5] = tmp.y; bs[6] = tmp.z; bs[7] = tmp.w;
    }

    auto ldrow = [&](int t, bool valid, float* dst) {
        if (valid) {
            half8 raw = h[(size_t)t * 512 + tid];
#pragma unroll
            for (int e = 0; e < 8; ++e) dst[e] = (float)raw[e];
        } else {
#pragma unroll
            for (int e = 0; e < 8; ++e) dst[e] = 0.f;
        }
    };

    float pv[8], cu[8], nx[8], pf[8];
    ldrow(t0 - 1, s0 > 0, pv);
    ldrow(t0, true, cu);
    ldrow(t0 + 1, true, nx);

#pragma unroll
    for (int i = 0; i < CT; ++i) {
        const int t = t0 + i;
        ldrow(t + 2, (s0 + i + 2) < S_, pf);

        float v[8];
        float mx = 0.f;
#pragma unroll
        for (int e = 0; e < 8; ++e) {
            float y = wc[3 * e] * pv[e] + wc[3 * e + 1] * cu[e] + wc[3 * e + 2] * nx[e] + bs[e];
            // silu(y) = y * sigmoid(y) = y * rcp(1 + 2^(-y*log2e))
            float ex = __builtin_amdgcn_exp2f(-1.44269504088896f * y);
            float r  = y * __builtin_amdgcn_rcpf(1.0f + ex);
            v[e] = r;
            mx = fmaxf(mx, fabsf(r));
        }
#pragma unroll
        for (int off = 32; off > 0; off >>= 1)
            mx = fmaxf(mx, __shfl_down(mx, off, 64));
        if ((tid & 63) == 0) red[i & 1][tid >> 6] = mx;
        __syncthreads();
        float rmax = red[i & 1][0];
#pragma unroll
        for (int w = 1; w < 8; ++w) rmax = fmaxf(rmax, red[i & 1][w]);
        float scale = 127.0f / fmaxf(rmax, 1e-5f);
        char8v o;
#pragma unroll
        for (int e = 0; e < 8; ++e)
            o[e] = (signed char)(int)rintf(v[e] * scale);
        q[(size_t)t * 512 + tid] = o;
        if (tid == 0) dq[t] = 1.0f / scale;
#pragma unroll
        for (int e = 0; e < 8; ++e) { pv[e] = cu[e]; cu[e] = nx[e]; nx[e] = pf[e]; }
    }
}

// ---------------------------------------------------------------------------
// GEMM1 round 7: BK=128 (2x MFMA work per sync unit -- the invariant r3/r5/r6
// never changed). BM=BN=256, 8 waves as 2(M)x4(N), wave-tile 128x64, acc[8][4],
// 64 MFMA/wave/K-tile, NT=8. Ring-2 LDS, 2 x 64KB = 128KB, 1 block/CU.
//
// LDS as ksub-planes: buf = { A[2 ksub][256 rows][64B], B[2][256][64] } so each
// half-K stage (32KB: A-ksub + B-ksub) is a contiguous gload_lds target, and
// the r2-r5-verified 64B-row swizzle (phys_chunk = chunk ^ ((row>>1)&3),
// involution on global source + ds_read) carries over unchanged.
//
// 4 phases per K-tile t (m201 shape: ds_read | stage | BAR | lgkm0 | 16 MFMA | BAR):
//  ph0: bf0[4]+af[0..3] (ksub0) | stage ksub0(t+1) | ... MFMA acc[0..3]
//  ph1: af[4..7] (ksub0)        |                  | ... MFMA acc[4..7] | vmcnt(4)
//  ph2: bf1[4]+af[0..3] (ksub1) | stage ksub1(t+1) | ... MFMA acc[0..3]
//  ph3: af[4..7] (ksub1)        |                  | ... MFMA acc[4..7] | vmcnt(4)
// Counted vmcnt (never 0 mid-loop): end-ph1 retires ksub1(t) (staged ph2(t-1),
// 3-phase latency cover; 8 outstanding -> 4); end-ph3 retires ksub0(t+1)
// (staged ph0(t), 4-phase cover). Barrier after each wait makes the per-wave
// guarantee cross-wave. Tail: last tile stages nothing -> vmcnt(0)/skip.
// Ring-2 recycle safety: stage(t+1) at ph0(t) overwrites the buffer whose last
// ds_reads (ph3(t-1)) retired before ph3(t-1)'s lgkm0+barrier in every wave.
__global__ __launch_bounds__(512, 2)
void gemm1_bk128(const int8_t* __restrict__ A, const int8_t* __restrict__ Bm,
                 _Float16* __restrict__ C, const float* __restrict__ rowdq,
                 const float* __restrict__ sc, int slot, int N, int K) {
    __shared__ __align__(16) int8_t lds[2][65536];   // [buf][A 32KB | B 32KB]
    const int tid  = threadIdx.x;
    const int lane = tid & 63;
    const int wave = tid >> 6;

    // XCD-chunked bijective swizzle (grid 512, multiple of 8)
    const int nwg = gridDim.x * gridDim.y;
    int flat = blockIdx.y * gridDim.x + blockIdx.x;
    flat = (flat & 7) * (nwg >> 3) + (flat >> 3);
    const int bx = flat % gridDim.x;
    const int by = flat / gridDim.x;
    const int mbase = by << 8;               // BM=256
    const int nbase = bx << 8;               // BN=256
    const int NT = K >> 7;                   // BK=128 -> 8

    const int wm = wave >> 2;                // 0..1  (128-row half)
    const int wn = wave & 3;                 // 0..3  (64-col quarter)

    // ---- staging: wave w covers A rows [32w,32w+32) and B rows [32w,32w+32)
    // per ksub-half; 2+2 gloads (1KB = 16 rows x 64B each). Inverse swizzle on
    // the global source.
    const int srow = lane >> 2;                               // 0..15 row in unit
    const int csrc = (((lane & 3) ^ ((lane >> 3) & 3)) << 4); // logical 16B chunk
    const int8_t* Ag = A  + (size_t)(mbase + wave * 32 + srow) * K + csrc;
    const int8_t* Bg = Bm + (size_t)(nbase + wave * 32 + srow) * K + csrc;

    // stage ksub s (64B half-rows) of K-tile tt into buffer b: 4 gloads/thread
    auto stage = [&](int b, int s, int tt) {
        const size_t ko = ((size_t)tt << 7) + ((size_t)s << 6);
        int8_t* dA = &lds[b][(s << 14) + (wave << 11)];
        int8_t* dB = &lds[b][32768 + (s << 14) + (wave << 11)];
        GLOAD_LDS16(Ag + ko,                  dA);
        GLOAD_LDS16(Ag + ko + (size_t)16 * K, dA + 1024);
        GLOAD_LDS16(Bg + ko,                  dB);
        GLOAD_LDS16(Bg + ko + (size_t)16 * K, dB + 1024);
    };

    // ---- frag read offsets (i8 16x16x64: row = lane&15, chunk = lane>>4)
    const int fc    = (((lane >> 4) ^ ((lane >> 1) & 3)) << 4);     // swizzled chunk
    const int abase = ((wm * 128 + (lane & 15)) << 6) + fc;         // + s*16384 + i*1024
    const int bbase = 32768 + ((wn * 64 + (lane & 15)) << 6) + fc;  // + s*16384 + j*1024

    v4i acc[8][4] = {};

    // prologue: tile 0 (both ksubs); counted wait for ksub0 only
    stage(0, 0, 0);
    stage(0, 1, 0);
    VMC4();
    sbar();

    for (int t = 0; t < NT; ++t) {
        const int8_t* base = &lds[t & 1][0];
        const int nb = (t & 1) ^ 1;
        const bool pf = (t + 1 < NT);

        v4i bf[4], af[4];

        // ---------------- phase 0: ksub0, rows 0-63 ----------------
#pragma unroll
        for (int j = 0; j < 4; ++j)
            bf[j] = *reinterpret_cast<const v4i*>(base + bbase + (j << 10));
#pragma unroll
        for (int i = 0; i < 4; ++i)
            af[i] = *reinterpret_cast<const v4i*>(base + abase + (i << 10));
        if (pf) stage(nb, 0, t + 1);
        sbar();
        LGKM0();
        __builtin_amdgcn_s_setprio(1);
#pragma unroll
        for (int i = 0; i < 4; ++i)
#pragma unroll
            for (int j = 0; j < 4; ++j)
                acc[i][j] = __builtin_amdgcn_mfma_i32_16x16x64_i8(af[i], bf[j], acc[i][j], 0, 0, 0);
        __builtin_amdgcn_s_setprio(0);
        sbar();

        // ---------------- phase 1: ksub0, rows 64-127 ----------------
#pragma unroll
        for (int i = 0; i < 4; ++i)
            af[i] = *reinterpret_cast<const v4i*>(base + abase + ((i + 4) << 10));
        sbar();
        LGKM0();
        __builtin_amdgcn_s_setprio(1);
#pragma unroll
        for (int i = 0; i < 4; ++i)
#pragma unroll
            for (int j = 0; j < 4; ++j)
                acc[i + 4][j] = __builtin_amdgcn_mfma_i32_16x16x64_i8(af[i], bf[j], acc[i + 4][j], 0, 0, 0);
        __builtin_amdgcn_s_setprio(0);
        if (pf) VMC4(); else VMC0();   // retire ksub1(t) (3-phase cover)
        sbar();

        // ---------------- phase 2: ksub1, rows 0-63 ----------------
#pragma unroll
        for (int j = 0; j < 4; ++j)
            bf[j] = *reinterpret_cast<const v4i*>(base + 16384 + bbase + (j << 10));
#pragma unroll
        for (int i = 0; i < 4; ++i)
            af[i] = *reinterpret_cast<const v4i*>(base + 16384 + abase + (i << 10));
        if (pf) stage(nb, 1, t + 1);
        sbar();
        LGKM0();
        __builtin_amdgcn_s_setprio(1);
#pragma unroll
        for (int i = 0; i < 4; ++i)
#pragma unroll
            for (int j = 0; j < 4; ++j)
                acc[i][j] = __builtin_amdgcn_mfma_i32_16x16x64_i8(af[i], bf[j], acc[i][j], 0, 0, 0);
        __builtin_amdgcn_s_setprio(0);
        sbar();

        // ---------------- phase 3: ksub1, rows 64-127 ----------------
#pragma unroll
        for (int i = 0; i < 4; ++i)
            af[i] = *reinterpret_cast<const v4i*>(base + 16384 + abase + ((i + 4) << 10));
        sbar();
        LGKM0();
        __builtin_amdgcn_s_setprio(1);
#pragma unroll
        for (int i = 0; i < 4; ++i)
#pragma unroll
            for (int j = 0; j < 4; ++j)
                acc[i + 4][j] = __builtin_amdgcn_mfma_i32_16x16x64_i8(af[i], bf[j], acc[i + 4][j], 0, 0, 0);
        __builtin_amdgcn_s_setprio(0);
        if (pf) VMC4();                 // retire ksub0(t+1) (4-phase cover)
        sbar();
    }

    // ---------------- epilogue ----------------
    const float wdq = sc[slot];
    const int quad = lane >> 4;
    const int col  = lane & 15;
#pragma unroll
    for (int i = 0; i < 8; ++i) {
#pragma unroll
        for (int r = 0; r < 4; ++r) {
            int m = mbase + (wm << 7) + (i << 4) + (quad << 2) + r;  // row=(lane>>4)*4+reg
            float rs = rowdq[m] * wdq;
#pragma unroll
            for (int j = 0; j < 4; ++j) {
                int n = nbase + (wn << 6) + (j << 4) + col;          // col=lane&15
                C[(size_t)m * N + n] = (_Float16)((float)acc[i][j][r] * rs);
            }
        }
    }
}

// ---------------------------------------------------------------------------
// GEMM2 kernel (grid-constrained by N=1024): BM=128/BN=128, 4 waves, BK=64,
// 3-deep ring, one barrier per tile, counted vmcnt. Unchanged from r3.
template <int BM, int WAVES, typename OutT>
__global__ __launch_bounds__(WAVES * 64, (BM == 256) ? 4 : 3)
void gemm_i8_bk64(const int8_t* __restrict__ A, const int8_t* __restrict__ Bm,
                  OutT* __restrict__ C, const float* __restrict__ rowdq,
                  const float* __restrict__ sc, int slot, int N, int K) {
    constexpr int BN = 128;
    constexpr int ABYTES = BM * 64;           // A bytes per ring buffer
    constexpr int BUF = (BM + BN) * 64;       // bytes per ring buffer
    constexpr int ALOADS = BM / 16 / WAVES;   // per-wave 1KB A loads per tile
    constexpr int BLOADS = BN / 16 / WAVES;   // per-wave 1KB B loads per tile
    constexpr int L = ALOADS + BLOADS;        // per-wave loads per tile

    __shared__ __align__(16) int8_t lds[3][BUF];
    const int tid  = threadIdx.x;
    const int lane = tid & 63;
    const int wave = tid >> 6;

    // XCD-chunked bijective swizzle (grid is a multiple of 8)
    const int nwg = gridDim.x * gridDim.y;
    int flat = blockIdx.y * gridDim.x + blockIdx.x;
    flat = (flat & 7) * (nwg >> 3) + (flat >> 3);
    const int bx = flat % gridDim.x;
    const int by = flat / gridDim.x;
    const int mbase = by * BM;
    const int nbase = bx << 7;
    const int NT = K >> 6;

    const int wm = wave >> 1;                 // m 64-row slab
    const int wn = wave & 1;                  // n 64-col half

    // ---- staging source addressing (inverse swizzle on global side)
    const int srow = lane >> 2;                               // row within 1KB load
    const int csrc = (((lane & 3) ^ ((lane >> 3) & 3)) << 4); // logical 16B chunk
    const int8_t* Ag = A  + (size_t)(mbase + wave * (ALOADS * 16) + srow) * K + csrc;
    const int8_t* Bg = Bm + (size_t)(nbase + wave * (BLOADS * 16) + srow) * K + csrc;

    auto stage = [&](int s, int tt) {
        const size_t ko = (size_t)tt << 6;
        int8_t* dA = &lds[s][(wave * ALOADS) << 10];
        int8_t* dB = &lds[s][ABYTES + ((wave * BLOADS) << 10)];
#pragma unroll
        for (int l = 0; l < ALOADS; ++l)
            GLOAD_LDS16(Ag + ko + (size_t)(l * 16) * K, dA + (l << 10));
#pragma unroll
        for (int l = 0; l < BLOADS; ++l)
            GLOAD_LDS16(Bg + ko + (size_t)(l * 16) * K, dB + (l << 10));
    };

    // ---- frag read offsets (i8 16x16x64: row = lane&15, chunk = lane>>4)
    const int fc   = (((lane >> 4) ^ ((lane >> 1) & 3)) << 4);  // swizzled chunk
    const int aoff = ((wm * 64 + (lane & 15)) << 6) + fc;       // + i*1024
    const int boff = ABYTES + ((wn * 64 + (lane & 15)) << 6) + fc;

    v4i acc[4][4] = {};

    // prologue: 2 tiles in flight; wait tile 0 (counted), cross-wave via barrier
    stage(0, 0);
    stage(1, 1);
    if constexpr (L == 3) VMC3(); else VMC4();
    sbar();

    int sb = 0;
    for (int t = 0; t < NT; ++t) {
        const int8_t* base = &lds[sb][0];
        v4i af[4], bf[4];
#pragma unroll
        for (int i = 0; i < 4; ++i)
            af[i] = *reinterpret_cast<const v4i*>(base + aoff + (i << 10));
#pragma unroll
        for (int j = 0; j < 4; ++j)
            bf[j] = *reinterpret_cast<const v4i*>(base + boff + (j << 10));
        int s2 = sb + 2; if (s2 >= 3) s2 -= 3;
        if (t + 2 < NT) stage(s2, t + 2);

        __builtin_amdgcn_s_setprio(1);
#pragma unroll
        for (int i = 0; i < 4; ++i)
#pragma unroll
            for (int j = 0; j < 4; ++j)
                acc[i][j] = __builtin_amdgcn_mfma_i32_16x16x64_i8(af[i], bf[j], acc[i][j], 0, 0, 0);
        __builtin_amdgcn_s_setprio(0);

        if (t + 2 < NT)      { if constexpr (L == 3) VMC3(); else VMC4(); }
        else if (t + 1 < NT) VMC0();
        sbar();
        if (++sb == 3) sb = 0;
    }

    // ---------------- epilogue ----------------
    const float wdq = sc[slot];
    const int quad = lane >> 4;
    const int col  = lane & 15;
#pragma unroll
    for (int i = 0; i < 4; ++i) {
#pragma unroll
        for (int r = 0; r < 4; ++r) {
            int m = mbase + (wm << 6) + (i << 4) + (quad << 2) + r;  // row=(lane>>4)*4+reg
            float rs = rowdq[m] * wdq;
#pragma unroll
            for (int j = 0; j < 4; ++j) {
                int n = nbase + (wn << 6) + (j << 4) + col;          // col=lane&15
                C[(size_t)m * N + n] = (OutT)((float)acc[i][j][r] * rs);
            }
        }
    }
}

// ---------------------------------------------------------------------------
extern "C" void kernel_launch(void* const* d_in, const int* in_sizes, int n_in,
                              void* d_out, int out_size, void* d_ws, size_t ws_size,
                              hipStream_t stream) {
    const float* x  = (const float*)d_in[0];  // [4,2048,1024]
    const float* w1 = (const float*)d_in[1];  // [4096,1024]
    const float* cw = (const float*)d_in[2];  // [4096,1,3]
    const float* cb = (const float*)d_in[3];  // [4096]
    const float* w2 = (const float*)d_in[4];  // [1024,4096]
    float* out = (float*)d_out;               // [4,2048,1024]
    char* ws = (char*)d_ws;

    // Workspace layout (16B-aligned)
    double* part  = (double*)(ws + 0);          // 2048 doubles
    float*  sc    = (float*)(ws + 16384);       // {scale_w1, dq_w1, scale_w2, dq_w2}
    float*  dqx   = (float*)(ws + 16640);       // 8192 floats
    float*  dqh   = (float*)(ws + 49408);       // 8192 floats
    int8_t* qw1   = (int8_t*)(ws + 82176);      // 4 MB
    int8_t* qw2   = (int8_t*)(ws + 4276480);    // 4 MB
    int8_t* qx    = (int8_t*)(ws + 8470784);    // 8 MB
    int8_t* qh    = (int8_t*)(ws + 16859392);   // 32 MB
    _Float16* h   = (_Float16*)(ws + 50413824); // 64 MB (fp16)

    absmean_partial<<<2048, 256, 0, stream>>>((const float4*)w1, (const float4*)w2, part);
    finalize_scales<<<1, 256, 0, stream>>>(part, sc);
    quant_all<<<16384, 256, 0, stream>>>((const float4*)w1, (const float4*)w2,
                                         (const float4*)x, (char4*)qw1, (char4*)qw2,
                                         (char4*)qx, dqx, sc);

    // GEMM1: M=8192, N=4096, K=1024 -> h (fp16); 512 blocks, 1 block/CU
    dim3 g1(DH / 256, NTOK / 256);
    gemm1_bk128<<<g1, 512, 0, stream>>>(qx, qw1, h, dqx, sc, 1, DH, DM);

    conv_silu_quant<<<NTOK / CT, 512, 0, stream>>>((const half8*)h, (const float4*)cw,
                                                   (const float4*)cb, (char8v*)qh, dqh);

    // GEMM2: M=8192, N=1024, K=4096 -> out (fp32); 512 blocks
    dim3 g2(DM / 128, NTOK / 128);
    gemm_i8_bk64<128, 4, float><<<g2, 256, 0, stream>>>(qh, qw2, out, dqh, sc, 3, DM, DH);
}